// Round 5
// baseline (196.327 us; speedup 1.0000x reference)
//
#include <hip/hip_runtime.h>

#define NN 4096
#define DD 512
#define HH 8
#define FF 64
#define LRELU_ALPHA 0.2f
#define SP 72    // k_hp LDS row stride in bf16 elems
#define ASP 64   // k_attn LDS row stride (XOR-swizzled)
#define JQ 1024  // j-quarter length

typedef __attribute__((ext_vector_type(8))) short bf16x8;
typedef __attribute__((ext_vector_type(4))) float f32x4;

__device__ __forceinline__ float f4c(const float4& v, int k) {
    return k == 0 ? v.x : (k == 1 ? v.y : (k == 2 ? v.z : v.w));
}
__device__ __forceinline__ void f4s(float4& v, int k, float x) {
    if (k == 0) v.x = x; else if (k == 1) v.y = x; else if (k == 2) v.z = x; else v.w = x;
}
__device__ __forceinline__ unsigned short f2bf(float x) {   // RNE float->bf16
    unsigned u = __float_as_uint(x);
    return (unsigned short)((u + 0x7fffu + ((u >> 16) & 1u)) >> 16);
}
__device__ __forceinline__ float bf2f(unsigned short h) {
    return __uint_as_float(((unsigned)h) << 16);
}
// monotone float<->uint key for atomicMax on arbitrary-sign floats
__device__ __forceinline__ unsigned fkey(float x) {
    unsigned u = __float_as_uint(x);
    return (u & 0x80000000u) ? ~u : (u | 0x80000000u);
}
__device__ __forceinline__ float funkey(unsigned k) {
    unsigned u = (k & 0x80000000u) ? (k ^ 0x80000000u) : ~k;
    return __uint_as_float(u);
}

// ================= Kernel 1: fused prep (unchanged from round 4) =================
__global__ __launch_bounds__(256) void k_prep(const int* __restrict__ adj,
                                              const float* __restrict__ W,
                                              unsigned long long* __restrict__ adjm,
                                              unsigned short* __restrict__ wt_hi,
                                              unsigned short* __restrict__ wt_lo,
                                              unsigned* __restrict__ mxkey,
                                              float* __restrict__ hpsum) {
    __shared__ unsigned long long shbuf[2080];   // 16640 B, aliased per branch
    int b = blockIdx.x, t = threadIdx.x;
    if (b < 1024) {
        int g = b >> 2, cq = b & 3;
        int r0 = g * 16;
        int lane = t & 63, wv = t >> 6;
        unsigned long long (*w64)[17] = (unsigned long long(*)[17])shbuf;
        for (int r = 0; r < 16; r++) {
            #pragma unroll
            for (int q = 0; q < 4; q++) {
                int col = cq * 1024 + q * 256 + t;
                unsigned long long m = __ballot(adj[(size_t)(r0 + r) * NN + col] > 0);
                if (lane == 0) w64[r][q * 4 + wv] = m;
            }
        }
        __syncthreads();
        for (int tt = wv; tt < 16; tt += 4) {
            unsigned long long wbits = w64[lane & 15][tt];
            unsigned long long my = 0;
            #pragma unroll
            for (int k = 0; k < 16; k++) {
                int shv = 32 * (k >> 3) + 8 * (lane >> 4) + (k & 7);
                unsigned long long bal = __ballot((unsigned)((wbits >> shv) & 1ULL));
                if (lane == k) my = bal;
            }
            if (lane < 16)
                adjm[((size_t)g * 64 + cq * 16 + tt) * 16 + lane] = my;
        }
    } else if (b < 1088) {
        float (*tile)[65] = (float(*)[65])shbuf;
        int idx = b - 1024;
        int h = idx >> 3;
        int d0 = (idx & 7) * 64;
        #pragma unroll
        for (int kidx = 0; kidx < 4; kidx++) {
            int id = t + 256 * kidx;
            int dd = id >> 4, f4i = (id & 15) * 4;
            float4 v = *(const float4*)(W + ((size_t)(h * DD + d0 + dd)) * FF + f4i);
            tile[dd][f4i] = v.x; tile[dd][f4i + 1] = v.y;
            tile[dd][f4i + 2] = v.z; tile[dd][f4i + 3] = v.w;
        }
        __syncthreads();
        int f = t >> 2, c = (t & 3) * 16;
        union { unsigned short s[16]; uint4 v[2]; } hb, lb;
        #pragma unroll
        for (int q = 0; q < 16; q++) {
            float v = tile[c + q][f];
            unsigned short hi = f2bf(v);
            hb.s[q] = hi;
            lb.s[q] = f2bf(v - bf2f(hi));
        }
        uint4* dh = (uint4*)(wt_hi + ((size_t)h * FF + f) * DD + d0 + c);
        uint4* dl = (uint4*)(wt_lo + ((size_t)h * FF + f) * DD + d0 + c);
        dh[0] = hb.v[0]; dh[1] = hb.v[1];
        dl[0] = lb.v[0]; dl[1] = lb.v[1];
    } else {
        if (t < 16) mxkey[t] = 0u;
        hpsum[t] = 0.f;
        hpsum[t + 256] = 0.f;
    }
}

// ================= Kernel 2: hp GEMM (unchanged from round 4) ========
__global__ __launch_bounds__(256) void k_hp_mfma(const float* __restrict__ hmat,
                                                 const unsigned short* __restrict__ whi,
                                                 const unsigned short* __restrict__ wlo,
                                                 const float* __restrict__ a,
                                                 unsigned short* __restrict__ hpT_hi,
                                                 float* __restrict__ fs,
                                                 float* __restrict__ fd,
                                                 float* __restrict__ hpsum,
                                                 unsigned* __restrict__ mxkey) {
    __shared__ char smem[4 * 64 * SP * 2];   // 36864 B
    unsigned short* ah = (unsigned short*)smem;
    unsigned short* al = ah + 64 * SP;
    unsigned short* bh = al + 64 * SP;
    unsigned short* bl = bh + 64 * SP;

    int t = threadIdx.x;
    int h = blockIdx.y;
    int n0 = blockIdx.x * 64;
    int lane = t & 63;
    int w = t >> 6;
    int R0 = (w >> 1) * 32, F0 = (w & 1) * 32;
    int am = lane & 15, aq = lane >> 4;
    int sr = t >> 2, sc = (t & 3) * 16;

    const float* gha = hmat + (size_t)(n0 + sr) * DD;
    const unsigned short* gbh = whi + ((size_t)h * FF + sr) * DD;
    const unsigned short* gbl = wlo + ((size_t)h * FF + sr) * DD;

    f32x4 acc[2][2] = {};
    for (int kk = 0; kk < DD; kk += 64) {
        {
            float4 p0 = *(const float4*)(gha + kk + sc);
            float4 p1 = *(const float4*)(gha + kk + sc + 4);
            float4 p2 = *(const float4*)(gha + kk + sc + 8);
            float4 p3 = *(const float4*)(gha + kk + sc + 12);
            union { unsigned short s[16]; uint4 v[2]; } hb, lb;
            #pragma unroll
            for (int q = 0; q < 16; q++) {
                float v = q < 4 ? f4c(p0, q) : q < 8 ? f4c(p1, q - 4)
                          : q < 12 ? f4c(p2, q - 8) : f4c(p3, q - 12);
                unsigned short hi = f2bf(v);
                hb.s[q] = hi;
                lb.s[q] = f2bf(v - bf2f(hi));
            }
            *(uint4*)(ah + sr * SP + sc) = hb.v[0]; *(uint4*)(ah + sr * SP + sc + 8) = hb.v[1];
            *(uint4*)(al + sr * SP + sc) = lb.v[0]; *(uint4*)(al + sr * SP + sc + 8) = lb.v[1];
        }
        {
            const uint4* s2 = (const uint4*)(gbh + kk + sc);
            const uint4* s3 = (const uint4*)(gbl + kk + sc);
            uint4 w0 = s2[0], w1 = s2[1], x0 = s3[0], x1 = s3[1];
            *(uint4*)(bh + sr * SP + sc) = w0; *(uint4*)(bh + sr * SP + sc + 8) = w1;
            *(uint4*)(bl + sr * SP + sc) = x0; *(uint4*)(bl + sr * SP + sc + 8) = x1;
        }
        __syncthreads();
        #pragma unroll
        for (int k2 = 0; k2 < 2; k2++) {
            int ko = k2 * 32 + aq * 8;
            bf16x8 a0h = *(const bf16x8*)(ah + (R0 + am) * SP + ko);
            bf16x8 a1h = *(const bf16x8*)(ah + (R0 + 16 + am) * SP + ko);
            bf16x8 a0l = *(const bf16x8*)(al + (R0 + am) * SP + ko);
            bf16x8 a1l = *(const bf16x8*)(al + (R0 + 16 + am) * SP + ko);
            bf16x8 b0h = *(const bf16x8*)(bh + (F0 + am) * SP + ko);
            bf16x8 b1h = *(const bf16x8*)(bh + (F0 + 16 + am) * SP + ko);
            bf16x8 b0l = *(const bf16x8*)(bl + (F0 + am) * SP + ko);
            bf16x8 b1l = *(const bf16x8*)(bl + (F0 + 16 + am) * SP + ko);
            acc[0][0] = __builtin_amdgcn_mfma_f32_16x16x32_bf16(a0h, b0h, acc[0][0], 0, 0, 0);
            acc[0][1] = __builtin_amdgcn_mfma_f32_16x16x32_bf16(a0h, b1h, acc[0][1], 0, 0, 0);
            acc[1][0] = __builtin_amdgcn_mfma_f32_16x16x32_bf16(a1h, b0h, acc[1][0], 0, 0, 0);
            acc[1][1] = __builtin_amdgcn_mfma_f32_16x16x32_bf16(a1h, b1h, acc[1][1], 0, 0, 0);
            acc[0][0] = __builtin_amdgcn_mfma_f32_16x16x32_bf16(a0h, b0l, acc[0][0], 0, 0, 0);
            acc[0][1] = __builtin_amdgcn_mfma_f32_16x16x32_bf16(a0h, b1l, acc[0][1], 0, 0, 0);
            acc[1][0] = __builtin_amdgcn_mfma_f32_16x16x32_bf16(a1h, b0l, acc[1][0], 0, 0, 0);
            acc[1][1] = __builtin_amdgcn_mfma_f32_16x16x32_bf16(a1h, b1l, acc[1][1], 0, 0, 0);
            acc[0][0] = __builtin_amdgcn_mfma_f32_16x16x32_bf16(a0l, b0h, acc[0][0], 0, 0, 0);
            acc[0][1] = __builtin_amdgcn_mfma_f32_16x16x32_bf16(a0l, b1h, acc[0][1], 0, 0, 0);
            acc[1][0] = __builtin_amdgcn_mfma_f32_16x16x32_bf16(a1l, b0h, acc[1][0], 0, 0, 0);
            acc[1][1] = __builtin_amdgcn_mfma_f32_16x16x32_bf16(a1l, b1h, acc[1][1], 0, 0, 0);
        }
        __syncthreads();
    }

    unsigned* tt = (unsigned*)smem;
    float* rs = (float*)(smem + 17408);
    float* rd = rs + 256;
    float* ash = rd + 256;
    if (t < 128) ash[t] = a[h * 2 * FF + t];
    int col = lane & 15, rbase = (lane >> 4) * 4;
    #pragma unroll
    for (int m16 = 0; m16 < 2; m16++) {
        #pragma unroll
        for (int n16 = 0; n16 < 2; n16++) {
            #pragma unroll
            for (int r = 0; r < 4; r++) {
                int nl = R0 + m16 * 16 + rbase + r;
                int f = F0 + n16 * 16 + col;
                float v = acc[m16][n16][r];
                unsigned short hi = f2bf(v);
                unsigned short lo = f2bf(v - bf2f(hi));
                tt[f * 68 + nl] = (unsigned)hi | ((unsigned)lo << 16);
            }
        }
    }
    __syncthreads();
    {
        int f = t >> 2, c = (t & 3) * 16;
        union { unsigned short s[16]; uint4 v[2]; } hb;
        float csum = 0.f;
        #pragma unroll
        for (int q = 0; q < 16; q++) {
            unsigned u = tt[f * 68 + c + q];
            hb.s[q] = (unsigned short)(u & 0xffffu);
            csum += bf2f((unsigned short)(u & 0xffffu)) + bf2f((unsigned short)(u >> 16));
        }
        uint4* dh = (uint4*)(hpT_hi + ((size_t)h * FF + f) * NN + n0 + c);
        dh[0] = hb.v[0]; dh[1] = hb.v[1];
        csum += __shfl_xor(csum, 1);
        csum += __shfl_xor(csum, 2);
        if ((t & 3) == 0) unsafeAtomicAdd(hpsum + h * FF + f, csum);
    }
    {
        int n = t & 63, g = t >> 6;
        float fsp = 0.f, fdp = 0.f;
        #pragma unroll
        for (int q = 0; q < 16; q++) {
            int f = g * 16 + q;
            unsigned u = tt[f * 68 + n];
            float v = bf2f((unsigned short)(u & 0xffffu)) + bf2f((unsigned short)(u >> 16));
            fsp += v * ash[f];
            fdp += v * ash[64 + f];
        }
        rs[g * 64 + n] = fsp;
        rd[g * 64 + n] = fdp;
    }
    __syncthreads();
    if (t < 64) {
        const float LOG2E = 1.44269504f;
        float fdv = (rd[t] + rd[64 + t] + rd[128 + t] + rd[192 + t]) * LOG2E;
        fs[(size_t)h * NN + n0 + t] = (rs[t] + rs[64 + t] + rs[128 + t] + rs[192 + t]) * LOG2E;
        fd[(size_t)h * NN + n0 + t] = fdv;
        unsigned key = fkey(fdv);
        #pragma unroll
        for (int off = 32; off; off >>= 1) key = max(key, (unsigned)__shfl_xor((int)key, off));
        if (t == 0) atomicMax(mxkey + h, key);
    }
}

// ================= Kernel 3: attention — j-split 4, 32 rows/wave, XOR-swizzled LDS ==========
// grid (NN/64, HH), 512 threads = 8 waves. Wave w: j-quarter jq = w>>1 (1024 cols),
// row-group rg = w&1 (32 i-rows via TWO P-fragment pairs). Each wave reads the same 8
// A-fragments per tile as round 4 but covers 2x the rows -> LDS read traffic halved.
// LDS: 2-dbuf x 4 quarter-tiles, ASP=64 + XOR swizzle (elem ^= (row&7)*8) on write+read.
// Cross-quarter combine in LDS. 16 waves/CU, no global atomics.
__global__ __launch_bounds__(512, 4) void k_attn(const float* __restrict__ fs,
                                                 const float* __restrict__ fd,
                                                 const unsigned* __restrict__ mxkey,
                                                 const unsigned long long* __restrict__ adjm,
                                                 const unsigned short* __restrict__ hpT_hi,
                                                 const float* __restrict__ hpsum,
                                                 float* __restrict__ outp) {
    __shared__ unsigned short hbh[2][4][64 * ASP];   // 65536 B

    int t = threadIdx.x;
    int h = blockIdx.y;
    int i0 = blockIdx.x * 64;
    int lane = t & 63;
    int w = t >> 6;              // 0..7
    int jq = w >> 1;             // j-quarter 0..3
    int rg = w & 1;              // row-group (32 rows)
    int am = lane & 15, aq = lane >> 4;
    int tq = t >> 7;             // staging: which quarter tile this thread fills
    int ts = t & 127;
    int sr = ts >> 1, sc = (ts & 1) * 32;     // 128 threads/tile: 64 rows x 2 col-halves
    int swr = (sr & 7) * 8;                   // write-side XOR (elems)
    int swa = (am & 7) * 8;                   // read-side XOR (rows am+16m share am&7)

    // per-row constants for both 16-row sub-frags
    float mfdL = funkey(mxkey[h]);
    float fsv0 = fs[(size_t)h * NN + i0 + rg * 32 + am];
    float fsv1 = fs[(size_t)h * NN + i0 + rg * 32 + 16 + am];
    float sL0 = fsv0 + mfdL, sL1 = fsv1 + mfdL;
    float mrL0 = fmaxf(sL0, LRELU_ALPHA * sL0), mrL1 = fmaxf(sL1, LRELU_ALPHA * sL1);
    float Ai0 = fsv0 - mrL0, Ci0 = -0.8f * mrL0;
    float Ai1 = fsv1 - mrL1, Ci1 = -0.8f * mrL1;

    int jqu = __builtin_amdgcn_readfirstlane(jq);
    int rgu = __builtin_amdgcn_readfirstlane(rg);
    const unsigned long long* mbA = adjm + ((size_t)(blockIdx.x * 4 + rgu * 2) * 64) * 16;
    const unsigned long long* mbB = mbA + (size_t)64 * 16;
    const unsigned short* gH = hpT_hi + (size_t)h * FF * NN;
    const float* fdh = fd + (size_t)h * NN + (size_t)jqu * JQ;   // wave's quarter

    f32x4 acc[2][4] = {};
    f32x4 accl[2] = {};
    bf16x8 ones;
    #pragma unroll
    for (int i = 0; i < 8; i++) ones[i] = (short)0x3f80;   // bf16 1.0

    auto stage_load = [&](int j0, uint4* v) {   // j0 relative to quarter
        const uint4* s = (const uint4*)(gH + (size_t)sr * NN + tq * JQ + j0 + sc);
        v[0] = s[0]; v[1] = s[1]; v[2] = s[2]; v[3] = s[3];
    };
    auto stage_write = [&](int buf, const uint4* v) {
        #pragma unroll
        for (int q = 0; q < 4; q++)
            *(uint4*)(&hbh[buf][tq][sr * ASP + ((sc + q * 8) ^ swr)]) = v[q];
    };
    auto fd_load = [&](int j0, float4* p) {
        p[0] = *(const float4*)(fdh + j0 + aq * 8);
        p[1] = *(const float4*)(fdh + j0 + aq * 8 + 4);
        p[2] = *(const float4*)(fdh + j0 + 32 + aq * 8);
        p[3] = *(const float4*)(fdh + j0 + 32 + aq * 8 + 4);
    };
    // 8 scores -> one bf16x8 B-fragment; masks are wave-uniform 64-bit lane masks
    auto mkfrag = [&](float4 p0, float4 p1, const unsigned long long* mk, int off,
                      float Ai, float Ci) -> bf16x8 {
        unsigned eu[8];
        #pragma unroll
        for (int q = 0; q < 2; q++) {
            float4 pv = q ? p1 : p0;
            #pragma unroll
            for (int bq = 0; bq < 4; bq++) {
                float tv = Ai + f4c(pv, bq);
                float uv = __builtin_fmaf(LRELU_ALPHA, tv, Ci);
                float ev = __builtin_amdgcn_exp2f(fmaxf(tv, uv));
                unsigned r;
                asm("v_cndmask_b32 %0, 0, %1, %2"
                    : "=v"(r) : "v"(ev), "s"(mk[off + q * 4 + bq]));
                eu[q * 4 + bq] = r;
            }
        }
        union { unsigned u[4]; bf16x8 v; } pk;
        pk.u[0] = __builtin_amdgcn_perm(eu[1], eu[0], 0x07060302);
        pk.u[1] = __builtin_amdgcn_perm(eu[3], eu[2], 0x07060302);
        pk.u[2] = __builtin_amdgcn_perm(eu[5], eu[4], 0x07060302);
        pk.u[3] = __builtin_amdgcn_perm(eu[7], eu[6], 0x07060302);
        return pk.v;
    };

    bf16x8 Pa0, Pa1, Pb0, Pb1;
    {   // prologue: tile 0 of each quarter
        uint4 v[4]; float4 pf[4];
        stage_load(0, v);
        fd_load(0, pf);
        unsigned long long mkA[16], mkB[16];
        size_t jt = (size_t)(jqu * 16) * 16;
        #pragma unroll
        for (int k = 0; k < 16; k++) { mkA[k] = mbA[jt + k]; mkB[k] = mbB[jt + k]; }
        Pa0 = mkfrag(pf[0], pf[1], mkA, 0, Ai0, Ci0);
        Pa1 = mkfrag(pf[2], pf[3], mkA, 8, Ai0, Ci0);
        Pb0 = mkfrag(pf[0], pf[1], mkB, 0, Ai1, Ci1);
        Pb1 = mkfrag(pf[2], pf[3], mkB, 8, Ai1, Ci1);
        stage_write(0, v);
        __syncthreads();
    }

    for (int j0 = 0; j0 < JQ; j0 += 64) {
        int cur = (j0 >> 6) & 1;
        int jn = (j0 + 64) & (JQ - 1);   // wraps on last iter; produce is harmless then
        uint4 v[4]; float4 pf[4];
        stage_load(jn, v);               // issue next-tile loads early (T14)
        fd_load(jn, pf);
        unsigned long long mkA[16], mkB[16];
        size_t jt = (size_t)(jqu * 16 + (jn >> 6)) * 16;
        #pragma unroll
        for (int k = 0; k < 16; k++) { mkA[k] = mbA[jt + k]; mkB[k] = mbB[jt + k]; }

        // consume current tile of this wave's quarter: 8 shared A-frags, 2 P-pairs
        #pragma unroll
        for (int k2 = 0; k2 < 2; k2++) {
            int ko = (k2 * 32 + aq * 8) ^ swa;
            bf16x8 x0 = *(const bf16x8*)(&hbh[cur][jq][(am)      * ASP + ko]);
            bf16x8 x1 = *(const bf16x8*)(&hbh[cur][jq][(am + 16) * ASP + ko]);
            bf16x8 x2 = *(const bf16x8*)(&hbh[cur][jq][(am + 32) * ASP + ko]);
            bf16x8 x3 = *(const bf16x8*)(&hbh[cur][jq][(am + 48) * ASP + ko]);
            bf16x8 PA = k2 ? Pa1 : Pa0;
            bf16x8 PB = k2 ? Pb1 : Pb0;
            acc[0][0] = __builtin_amdgcn_mfma_f32_16x16x32_bf16(x0, PA, acc[0][0], 0, 0, 0);
            acc[0][1] = __builtin_amdgcn_mfma_f32_16x16x32_bf16(x1, PA, acc[0][1], 0, 0, 0);
            acc[0][2] = __builtin_amdgcn_mfma_f32_16x16x32_bf16(x2, PA, acc[0][2], 0, 0, 0);
            acc[0][3] = __builtin_amdgcn_mfma_f32_16x16x32_bf16(x3, PA, acc[0][3], 0, 0, 0);
            accl[0]   = __builtin_amdgcn_mfma_f32_16x16x32_bf16(ones, PA, accl[0], 0, 0, 0);
            acc[1][0] = __builtin_amdgcn_mfma_f32_16x16x32_bf16(x0, PB, acc[1][0], 0, 0, 0);
            acc[1][1] = __builtin_amdgcn_mfma_f32_16x16x32_bf16(x1, PB, acc[1][1], 0, 0, 0);
            acc[1][2] = __builtin_amdgcn_mfma_f32_16x16x32_bf16(x2, PB, acc[1][2], 0, 0, 0);
            acc[1][3] = __builtin_amdgcn_mfma_f32_16x16x32_bf16(x3, PB, acc[1][3], 0, 0, 0);
            accl[1]   = __builtin_amdgcn_mfma_f32_16x16x32_bf16(ones, PB, accl[1], 0, 0, 0);
        }

        stage_write(cur ^ 1, v);         // write next hp tiles (other buffer)
        Pa0 = mkfrag(pf[0], pf[1], mkA, 0, Ai0, Ci0);
        Pa1 = mkfrag(pf[2], pf[3], mkA, 8, Ai0, Ci0);
        Pb0 = mkfrag(pf[0], pf[1], mkB, 0, Ai1, Ci1);
        Pb1 = mkfrag(pf[2], pf[3], mkB, 8, Ai1, Ci1);
        __syncthreads();
    }

    // Cross-quarter combine in LDS (reuse staging buffer), then normalize + ELU + store.
    float* cb  = (float*)hbh;            // 6 waves x 2048 floats = 48 KB
    float* cbl = cb + 12288;             // 6 x 128 floats
    if (jq != 0) {
        int idx = (jq - 1) * 2 + rg;     // 0..5
        float* wb = cb + idx * 2048;
        #pragma unroll
        for (int g = 0; g < 2; g++)
            #pragma unroll
            for (int mf = 0; mf < 4; mf++)
                *(f32x4*)&wb[((g * 4 + mf) * 64 + lane) * 4] = acc[g][mf];
        cbl[idx * 128 + 0 * 64 + lane] = accl[0][0];
        cbl[idx * 128 + 1 * 64 + lane] = accl[1][0];
    }
    __syncthreads();
    if (jq == 0) {
        float li[2] = { accl[0][0], accl[1][0] };
        #pragma unroll
        for (int q = 0; q < 3; q++) {
            int idx = q * 2 + rg;
            float* wb = cb + idx * 2048;
            #pragma unroll
            for (int g = 0; g < 2; g++) {
                #pragma unroll
                for (int mf = 0; mf < 4; mf++)
                    acc[g][mf] += *(const f32x4*)&wb[((g * 4 + mf) * 64 + lane) * 4];
                li[g] += cbl[idx * 128 + g * 64 + lane];
            }
        }
        const float invN = 1.0f / NN;
        #pragma unroll
        for (int g = 0; g < 2; g++) {
            float lg = li[g];
            float rl = 1.f / lg;
            int row = i0 + rg * 32 + g * 16 + am;
            float* orow = outp + (size_t)row * (HH * FF) + h * FF;
            #pragma unroll
            for (int mf = 0; mf < 4; mf++) {
                float4 ov;
                #pragma unroll
                for (int r = 0; r < 4; r++) {
                    int f = mf * 16 + aq * 4 + r;
                    float v;
                    if (lg > 0.f) v = acc[g][mf][r] * rl;
                    else          v = hpsum[h * FF + f] * invN;   // all-masked row fallback
                    v = v > 0.f ? v : __expf(v) - 1.f;
                    f4s(ov, r, v);
                }
                *(float4*)(orow + mf * 16 + aq * 4) = ov;
            }
        }
    }
}

extern "C" void kernel_launch(void* const* d_in, const int* in_sizes, int n_in,
                              void* d_out, int out_size, void* d_ws, size_t ws_size,
                              hipStream_t stream) {
    const float* hmat = (const float*)d_in[0];
    const int*   adj  = (const int*)d_in[1];
    const float* W    = (const float*)d_in[2];
    const float* a    = (const float*)d_in[3];
    float* out = (float*)d_out;

    char* ws = (char*)d_ws;
    unsigned short* hpT_hi = (unsigned short*)(ws);                 // 4 MB
    unsigned long long* adjm = (unsigned long long*)(ws + (4u << 20)); // 2 MB
    unsigned short* wt_hi  = (unsigned short*)(ws + (6u << 20));    // 512 KB
    unsigned short* wt_lo  = (unsigned short*)(ws + (6u << 20) + (512u << 10));
    float* fs    = (float*)(ws + (7u << 20));                       // 128 KB
    float* fd    = (float*)(ws + (7u << 20) + (128u << 10));        // 128 KB
    unsigned* mxkey = (unsigned*)(ws + (7u << 20) + (256u << 10));  // 64 B
    float* hpsum = (float*)(mxkey + 16);                            // 2 KB

    k_prep   <<<dim3(1089),          256, 0, stream>>>(adj, W, adjm, wt_hi, wt_lo,
                                                       mxkey, hpsum);
    k_hp_mfma<<<dim3(64, 8),         256, 0, stream>>>(hmat, wt_hi, wt_lo, a,
                                                       hpT_hi, fs, fd, hpsum, mxkey);
    k_attn   <<<dim3(NN / 64, HH),   512, 0, stream>>>(fs, fd, mxkey, adjm,
                                                       hpT_hi, hpsum, out);
}

// Round 6
// 177.219 us; speedup vs baseline: 1.1078x; 1.1078x over previous
//
#include <hip/hip_runtime.h>

#define NN 4096
#define DD 512
#define HH 8
#define FF 64
#define LRELU_ALPHA 0.2f
#define SP 72   // LDS row stride in bf16 elems
#define JSPLIT 2
#define JCHUNK (NN / JSPLIT)

typedef __attribute__((ext_vector_type(8))) short bf16x8;
typedef __attribute__((ext_vector_type(4))) float f32x4;

__device__ __forceinline__ float f4c(const float4& v, int k) {
    return k == 0 ? v.x : (k == 1 ? v.y : (k == 2 ? v.z : v.w));
}
__device__ __forceinline__ void f4s(float4& v, int k, float x) {
    if (k == 0) v.x = x; else if (k == 1) v.y = x; else if (k == 2) v.z = x; else v.w = x;
}
__device__ __forceinline__ unsigned short f2bf(float x) {   // RNE float->bf16
    unsigned u = __float_as_uint(x);
    return (unsigned short)((u + 0x7fffu + ((u >> 16) & 1u)) >> 16);
}
__device__ __forceinline__ float bf2f(unsigned short h) {
    return __uint_as_float(((unsigned)h) << 16);
}
// monotone float<->uint key for atomicMax on arbitrary-sign floats
__device__ __forceinline__ unsigned fkey(float x) {
    unsigned u = __float_as_uint(x);
    return (u & 0x80000000u) ? ~u : (u | 0x80000000u);
}
__device__ __forceinline__ float funkey(unsigned k) {
    unsigned u = (k & 0x80000000u) ? (k ^ 0x80000000u) : ~k;
    return __uint_as_float(u);
}

// ================= Kernel 1: fused prep =================
// [0,2048)     : adjacency -> lane-indexed 64-bit MFMA masks adjm[g][t][16]
//                block b: g = b>>3 (16-row group), cs = b&7 (512-col segment).
//                Same output layout as before; 2x blocks, half the serial load depth.
// [2048,2112)  : split+transpose W -> wt_hi/wt_lo [h][f][d]
// [2112,2368)  : one-shot hi/lo split of hmat -> h_hi/h_lo [n][d] bf16 (hoisted from k_hp)
// 2368         : zero mxkey + hpsum
__global__ __launch_bounds__(256) void k_prep(const int* __restrict__ adj,
                                              const float* __restrict__ W,
                                              const float* __restrict__ hmat,
                                              unsigned long long* __restrict__ adjm,
                                              unsigned short* __restrict__ wt_hi,
                                              unsigned short* __restrict__ wt_lo,
                                              unsigned short* __restrict__ h_hi,
                                              unsigned short* __restrict__ h_lo,
                                              unsigned* __restrict__ mxkey,
                                              float* __restrict__ hpsum) {
    __shared__ unsigned long long shbuf[2080];   // 16640 B, aliased per branch
    int b = blockIdx.x, t = threadIdx.x;
    if (b < 2048) {
        int g = b >> 3, cs = b & 7;
        int r0 = g * 16;
        int lane = t & 63, wv = t >> 6;
        unsigned long long (*w64)[9] = (unsigned long long(*)[9])shbuf;
        // phase 1: coalesced row-pack of 16 rows x 512 cols into LDS words
        for (int r = 0; r < 16; r++) {
            #pragma unroll
            for (int q = 0; q < 2; q++) {
                int col = cs * 512 + q * 256 + t;
                unsigned long long m = __ballot(adj[(size_t)(r0 + r) * NN + col] > 0);
                if (lane == 0) w64[r][q * 4 + wv] = m;
            }
        }
        __syncthreads();
        // phase 2: transpose-repack into lane-indexed MFMA masks via ballot
        for (int tl = wv; tl < 8; tl += 4) {
            unsigned long long wbits = w64[lane & 15][tl];
            unsigned long long my = 0;
            #pragma unroll
            for (int k = 0; k < 16; k++) {
                int shv = 32 * (k >> 3) + 8 * (lane >> 4) + (k & 7);
                unsigned long long bal = __ballot((unsigned)((wbits >> shv) & 1ULL));
                if (lane == k) my = bal;
            }
            if (lane < 16)
                adjm[((size_t)g * 64 + cs * 8 + tl) * 16 + lane] = my;
        }
    } else if (b < 2112) {
        float (*tile)[65] = (float(*)[65])shbuf;
        int idx = b - 2048;
        int h = idx >> 3;
        int d0 = (idx & 7) * 64;
        #pragma unroll
        for (int kidx = 0; kidx < 4; kidx++) {
            int id = t + 256 * kidx;
            int dd = id >> 4, f4i = (id & 15) * 4;
            float4 v = *(const float4*)(W + ((size_t)(h * DD + d0 + dd)) * FF + f4i);
            tile[dd][f4i] = v.x; tile[dd][f4i + 1] = v.y;
            tile[dd][f4i + 2] = v.z; tile[dd][f4i + 3] = v.w;
        }
        __syncthreads();
        int f = t >> 2, c = (t & 3) * 16;
        union { unsigned short s[16]; uint4 v[2]; } hb, lb;
        #pragma unroll
        for (int q = 0; q < 16; q++) {
            float v = tile[c + q][f];
            unsigned short hi = f2bf(v);
            hb.s[q] = hi;
            lb.s[q] = f2bf(v - bf2f(hi));
        }
        uint4* dh = (uint4*)(wt_hi + ((size_t)h * FF + f) * DD + d0 + c);
        uint4* dl = (uint4*)(wt_lo + ((size_t)h * FF + f) * DD + d0 + c);
        dh[0] = hb.v[0]; dh[1] = hb.v[1];
        dl[0] = lb.v[0]; dl[1] = lb.v[1];
    } else if (b < 2368) {
        // one-shot hi/lo split of hmat (bit-identical to the old in-k_hp split)
        int idx = b - 2112;                  // 0..255, 16 rows each
        int row = idx * 16 + (t >> 4);
        int c0 = (t & 15) * 32;
        const float* src = hmat + (size_t)row * DD + c0;
        #pragma unroll
        for (int half = 0; half < 2; half++) {
            float4 p0 = *(const float4*)(src + half * 16);
            float4 p1 = *(const float4*)(src + half * 16 + 4);
            float4 p2 = *(const float4*)(src + half * 16 + 8);
            float4 p3 = *(const float4*)(src + half * 16 + 12);
            union { unsigned short s[16]; uint4 v[2]; } hb, lb;
            #pragma unroll
            for (int q = 0; q < 16; q++) {
                float v = q < 4 ? f4c(p0, q) : q < 8 ? f4c(p1, q - 4)
                          : q < 12 ? f4c(p2, q - 8) : f4c(p3, q - 12);
                unsigned short hi = f2bf(v);
                hb.s[q] = hi;
                lb.s[q] = f2bf(v - bf2f(hi));
            }
            uint4* dh = (uint4*)(h_hi + (size_t)row * DD + c0 + half * 16);
            uint4* dl = (uint4*)(h_lo + (size_t)row * DD + c0 + half * 16);
            dh[0] = hb.v[0]; dh[1] = hb.v[1];
            dl[0] = lb.v[0]; dl[1] = lb.v[1];
        }
    } else {
        if (t < 16) mxkey[t] = 0u;
        hpsum[t] = 0.f;
        hpsum[t + 256] = 0.f;
    }
}

// ================= Kernel 2: hp GEMM (pre-split h_hi/h_lo; MFMA 3-product) ========
// Staging is now pure uint4 copies (split hoisted to k_prep). MFMA/epilogue unchanged.
__global__ __launch_bounds__(256) void k_hp_mfma(const unsigned short* __restrict__ hhi,
                                                 const unsigned short* __restrict__ hlo,
                                                 const unsigned short* __restrict__ whi,
                                                 const unsigned short* __restrict__ wlo,
                                                 const float* __restrict__ a,
                                                 unsigned short* __restrict__ hpT_hi,
                                                 float* __restrict__ fs,
                                                 float* __restrict__ fd,
                                                 float* __restrict__ hpsum,
                                                 unsigned* __restrict__ mxkey) {
    __shared__ char smem[4 * 64 * SP * 2];   // 36864 B
    unsigned short* ah = (unsigned short*)smem;
    unsigned short* al = ah + 64 * SP;
    unsigned short* bh = al + 64 * SP;
    unsigned short* bl = bh + 64 * SP;

    int t = threadIdx.x;
    int h = blockIdx.y;
    int n0 = blockIdx.x * 64;
    int lane = t & 63;
    int w = t >> 6;
    int R0 = (w >> 1) * 32, F0 = (w & 1) * 32;
    int am = lane & 15, aq = lane >> 4;
    int sr = t >> 2, sc = (t & 3) * 16;

    const unsigned short* ghh = hhi + (size_t)(n0 + sr) * DD;
    const unsigned short* ghl = hlo + (size_t)(n0 + sr) * DD;
    const unsigned short* gbh = whi + ((size_t)h * FF + sr) * DD;
    const unsigned short* gbl = wlo + ((size_t)h * FF + sr) * DD;

    f32x4 acc[2][2] = {};
    for (int kk = 0; kk < DD; kk += 64) {
        {   // h: pre-split bf16 hi/lo copies
            const uint4* s0 = (const uint4*)(ghh + kk + sc);
            const uint4* s1 = (const uint4*)(ghl + kk + sc);
            uint4 h0 = s0[0], h1 = s0[1], l0 = s1[0], l1 = s1[1];
            *(uint4*)(ah + sr * SP + sc) = h0; *(uint4*)(ah + sr * SP + sc + 8) = h1;
            *(uint4*)(al + sr * SP + sc) = l0; *(uint4*)(al + sr * SP + sc + 8) = l1;
        }
        {
            const uint4* s2 = (const uint4*)(gbh + kk + sc);
            const uint4* s3 = (const uint4*)(gbl + kk + sc);
            uint4 w0 = s2[0], w1 = s2[1], x0 = s3[0], x1 = s3[1];
            *(uint4*)(bh + sr * SP + sc) = w0; *(uint4*)(bh + sr * SP + sc + 8) = w1;
            *(uint4*)(bl + sr * SP + sc) = x0; *(uint4*)(bl + sr * SP + sc + 8) = x1;
        }
        __syncthreads();
        #pragma unroll
        for (int k2 = 0; k2 < 2; k2++) {
            int ko = k2 * 32 + aq * 8;
            bf16x8 a0h = *(const bf16x8*)(ah + (R0 + am) * SP + ko);
            bf16x8 a1h = *(const bf16x8*)(ah + (R0 + 16 + am) * SP + ko);
            bf16x8 a0l = *(const bf16x8*)(al + (R0 + am) * SP + ko);
            bf16x8 a1l = *(const bf16x8*)(al + (R0 + 16 + am) * SP + ko);
            bf16x8 b0h = *(const bf16x8*)(bh + (F0 + am) * SP + ko);
            bf16x8 b1h = *(const bf16x8*)(bh + (F0 + 16 + am) * SP + ko);
            bf16x8 b0l = *(const bf16x8*)(bl + (F0 + am) * SP + ko);
            bf16x8 b1l = *(const bf16x8*)(bl + (F0 + 16 + am) * SP + ko);
            acc[0][0] = __builtin_amdgcn_mfma_f32_16x16x32_bf16(a0h, b0h, acc[0][0], 0, 0, 0);
            acc[0][1] = __builtin_amdgcn_mfma_f32_16x16x32_bf16(a0h, b1h, acc[0][1], 0, 0, 0);
            acc[1][0] = __builtin_amdgcn_mfma_f32_16x16x32_bf16(a1h, b0h, acc[1][0], 0, 0, 0);
            acc[1][1] = __builtin_amdgcn_mfma_f32_16x16x32_bf16(a1h, b1h, acc[1][1], 0, 0, 0);
            acc[0][0] = __builtin_amdgcn_mfma_f32_16x16x32_bf16(a0h, b0l, acc[0][0], 0, 0, 0);
            acc[0][1] = __builtin_amdgcn_mfma_f32_16x16x32_bf16(a0h, b1l, acc[0][1], 0, 0, 0);
            acc[1][0] = __builtin_amdgcn_mfma_f32_16x16x32_bf16(a1h, b0l, acc[1][0], 0, 0, 0);
            acc[1][1] = __builtin_amdgcn_mfma_f32_16x16x32_bf16(a1h, b1l, acc[1][1], 0, 0, 0);
            acc[0][0] = __builtin_amdgcn_mfma_f32_16x16x32_bf16(a0l, b0h, acc[0][0], 0, 0, 0);
            acc[0][1] = __builtin_amdgcn_mfma_f32_16x16x32_bf16(a0l, b1h, acc[0][1], 0, 0, 0);
            acc[1][0] = __builtin_amdgcn_mfma_f32_16x16x32_bf16(a1l, b0h, acc[1][0], 0, 0, 0);
            acc[1][1] = __builtin_amdgcn_mfma_f32_16x16x32_bf16(a1l, b1h, acc[1][1], 0, 0, 0);
        }
        __syncthreads();
    }

    // Epilogue: pack hi/lo to LDS [f][n], store hi, fs/fd (scaled by LOG2E), maxfd, hpsum.
    unsigned* tt = (unsigned*)smem;
    float* rs = (float*)(smem + 17408);
    float* rd = rs + 256;
    float* ash = rd + 256;
    if (t < 128) ash[t] = a[h * 2 * FF + t];
    int col = lane & 15, rbase = (lane >> 4) * 4;
    #pragma unroll
    for (int m16 = 0; m16 < 2; m16++) {
        #pragma unroll
        for (int n16 = 0; n16 < 2; n16++) {
            #pragma unroll
            for (int r = 0; r < 4; r++) {
                int nl = R0 + m16 * 16 + rbase + r;
                int f = F0 + n16 * 16 + col;
                float v = acc[m16][n16][r];
                unsigned short hi = f2bf(v);
                unsigned short lo = f2bf(v - bf2f(hi));
                tt[f * 68 + nl] = (unsigned)hi | ((unsigned)lo << 16);
            }
        }
    }
    __syncthreads();
    {
        int f = t >> 2, c = (t & 3) * 16;
        union { unsigned short s[16]; uint4 v[2]; } hb;
        float csum = 0.f;
        #pragma unroll
        for (int q = 0; q < 16; q++) {
            unsigned u = tt[f * 68 + c + q];
            hb.s[q] = (unsigned short)(u & 0xffffu);
            csum += bf2f((unsigned short)(u & 0xffffu)) + bf2f((unsigned short)(u >> 16));
        }
        uint4* dh = (uint4*)(hpT_hi + ((size_t)h * FF + f) * NN + n0 + c);
        dh[0] = hb.v[0]; dh[1] = hb.v[1];
        csum += __shfl_xor(csum, 1);
        csum += __shfl_xor(csum, 2);
        if ((t & 3) == 0) unsafeAtomicAdd(hpsum + h * FF + f, csum);
    }
    {
        int n = t & 63, g = t >> 6;
        float fsp = 0.f, fdp = 0.f;
        #pragma unroll
        for (int q = 0; q < 16; q++) {
            int f = g * 16 + q;
            unsigned u = tt[f * 68 + n];
            float v = bf2f((unsigned short)(u & 0xffffu)) + bf2f((unsigned short)(u >> 16));
            fsp += v * ash[f];
            fdp += v * ash[64 + f];
        }
        rs[g * 64 + n] = fsp;
        rd[g * 64 + n] = fdp;
    }
    __syncthreads();
    if (t < 64) {
        const float LOG2E = 1.44269504f;
        float fdv = (rd[t] + rd[64 + t] + rd[128 + t] + rd[192 + t]) * LOG2E;
        fs[(size_t)h * NN + n0 + t] = (rs[t] + rs[64 + t] + rs[128 + t] + rs[192 + t]) * LOG2E;
        fd[(size_t)h * NN + n0 + t] = fdv;
        unsigned key = fkey(fdv);
        #pragma unroll
        for (int off = 32; off; off >>= 1) key = max(key, (unsigned)__shfl_xor((int)key, off));
        if (t == 0) atomicMax(mxkey + h, key);
    }
}

// ================= Kernel 3: attention — ROUND-4 VERBATIM (verified 47.8 us) ============
// grid (NN/64, HH), 512 threads = 8 waves. Wave w: j-half h2 = w>>2 (2048 cols),
// row-group rg = w&3 (16 i-rows). One barrier per 64-j iteration; LDS combine epilogue.
__global__ __launch_bounds__(512) void k_attn(const float* __restrict__ fs,
                                              const float* __restrict__ fd,
                                              const unsigned* __restrict__ mxkey,
                                              const unsigned long long* __restrict__ adjm,
                                              const unsigned short* __restrict__ hpT_hi,
                                              const float* __restrict__ hpsum,
                                              float* __restrict__ outp) {
    __shared__ unsigned short hbh[2][2][64 * SP];   // [dbuf][j-half][f*SP+j] = 36864 B

    int t = threadIdx.x;
    int h = blockIdx.y;
    int i0 = blockIdx.x * 64;
    int lane = t & 63;
    int w = t >> 6;              // 0..7
    int h2 = w >> 2;             // j-half
    int rg = w & 3;              // row-group
    int am = lane & 15, aq = lane >> 4;
    int th = t >> 8;             // staging: which half's tile this thread fills
    int ts = t & 255;
    int sr = ts >> 2, sc = (ts & 3) * 16;

    // per-row constants (scaled domain): arg = max(tv, 0.2*tv + Ci), tv = Ai + fdL_j
    float mfdL = funkey(mxkey[h]);
    float fsv = fs[(size_t)h * NN + i0 + rg * 16 + am];
    float sL = fsv + mfdL;
    float mrL = fmaxf(sL, LRELU_ALPHA * sL);
    float Ai = fsv - mrL;
    float Ci = -0.8f * mrL;

    int rgu = __builtin_amdgcn_readfirstlane(rg);
    int h2u = __builtin_amdgcn_readfirstlane(h2);
    const unsigned long long* mbase = adjm + ((size_t)(blockIdx.x * 4 + rgu) * 64) * 16;
    const unsigned short* gH = hpT_hi + (size_t)h * FF * NN;
    const float* fdh = fd + (size_t)h * NN + (size_t)h2u * JCHUNK;   // wave's half

    f32x4 acc[4] = {};
    f32x4 accl = {};
    bf16x8 ones;
    #pragma unroll
    for (int i = 0; i < 8; i++) ones[i] = (short)0x3f80;   // bf16 1.0

    auto stage_load = [&](int j0, uint4& v0, uint4& v1) {   // j0 relative to half
        const uint4* s = (const uint4*)(gH + (size_t)sr * NN + th * JCHUNK + j0 + sc);
        v0 = s[0]; v1 = s[1];
    };
    auto stage_write = [&](int buf, uint4 v0, uint4 v1) {
        *(uint4*)(&hbh[buf][th][sr * SP + sc]) = v0;
        *(uint4*)(&hbh[buf][th][sr * SP + sc + 8]) = v1;
    };
    auto fd_load = [&](int j0, float4* p) {
        p[0] = *(const float4*)(fdh + j0 + aq * 8);
        p[1] = *(const float4*)(fdh + j0 + aq * 8 + 4);
        p[2] = *(const float4*)(fdh + j0 + 32 + aq * 8);
        p[3] = *(const float4*)(fdh + j0 + 32 + aq * 8 + 4);
    };
    // 8 scores -> one bf16x8 B-fragment; masks are wave-uniform 64-bit lane masks
    auto mkfrag = [&](float4 p0, float4 p1, const unsigned long long* mk, int off) -> bf16x8 {
        unsigned eu[8];
        #pragma unroll
        for (int q = 0; q < 2; q++) {
            float4 pv = q ? p1 : p0;
            #pragma unroll
            for (int bq = 0; bq < 4; bq++) {
                float tv = Ai + f4c(pv, bq);
                float uv = __builtin_fmaf(LRELU_ALPHA, tv, Ci);
                float ev = __builtin_amdgcn_exp2f(fmaxf(tv, uv));
                unsigned r;
                asm("v_cndmask_b32 %0, 0, %1, %2"
                    : "=v"(r) : "v"(ev), "s"(mk[off + q * 4 + bq]));
                eu[q * 4 + bq] = r;
            }
        }
        union { unsigned u[4]; bf16x8 v; } pk;
        pk.u[0] = __builtin_amdgcn_perm(eu[1], eu[0], 0x07060302);
        pk.u[1] = __builtin_amdgcn_perm(eu[3], eu[2], 0x07060302);
        pk.u[2] = __builtin_amdgcn_perm(eu[5], eu[4], 0x07060302);
        pk.u[3] = __builtin_amdgcn_perm(eu[7], eu[6], 0x07060302);
        return pk.v;
    };

    bf16x8 Pc0, Pc1;
    {   // prologue: tile 0 of each half
        uint4 v0, v1; float4 pf[4];
        stage_load(0, v0, v1);
        fd_load(0, pf);
        unsigned long long mk[16];
        #pragma unroll
        for (int k = 0; k < 16; k++) mk[k] = mbase[(size_t)(h2u * 32) * 16 + k];
        Pc0 = mkfrag(pf[0], pf[1], mk, 0);
        Pc1 = mkfrag(pf[2], pf[3], mk, 8);
        stage_write(0, v0, v1);
        __syncthreads();
    }

    for (int j0 = 0; j0 < JCHUNK; j0 += 64) {
        int cur = (j0 >> 6) & 1;
        int jn = (j0 + 64) & (JCHUNK - 1);   // wraps on last iter; produce is harmless then
        uint4 v0, v1; float4 pf[4];
        stage_load(jn, v0, v1);              // issue next-tile loads early (T14)
        fd_load(jn, pf);
        unsigned long long mk[16];
        #pragma unroll
        for (int k = 0; k < 16; k++) mk[k] = mbase[(size_t)(h2u * 32 + (jn >> 6)) * 16 + k];

        // consume current tile of this wave's half: hp A-frags from LDS, P from registers
        #pragma unroll
        for (int k2 = 0; k2 < 2; k2++) {
            int ko = k2 * 32 + aq * 8;
            bf16x8 x0 = *(const bf16x8*)(&hbh[cur][h2][(am)      * SP + ko]);
            bf16x8 x1 = *(const bf16x8*)(&hbh[cur][h2][(am + 16) * SP + ko]);
            bf16x8 x2 = *(const bf16x8*)(&hbh[cur][h2][(am + 32) * SP + ko]);
            bf16x8 x3 = *(const bf16x8*)(&hbh[cur][h2][(am + 48) * SP + ko]);
            bf16x8 P = k2 ? Pc1 : Pc0;
            acc[0] = __builtin_amdgcn_mfma_f32_16x16x32_bf16(x0, P, acc[0], 0, 0, 0);
            acc[1] = __builtin_amdgcn_mfma_f32_16x16x32_bf16(x1, P, acc[1], 0, 0, 0);
            acc[2] = __builtin_amdgcn_mfma_f32_16x16x32_bf16(x2, P, acc[2], 0, 0, 0);
            acc[3] = __builtin_amdgcn_mfma_f32_16x16x32_bf16(x3, P, acc[3], 0, 0, 0);
            accl   = __builtin_amdgcn_mfma_f32_16x16x32_bf16(ones, P, accl, 0, 0, 0);
        }

        stage_write(cur ^ 1, v0, v1);        // write next hp tile (other buffer)
        Pc0 = mkfrag(pf[0], pf[1], mk, 0);
        Pc1 = mkfrag(pf[2], pf[3], mk, 8);
        __syncthreads();
    }

    // Cross-half combine in LDS (reuse staging buffer), then normalize + ELU + store.
    float* cb = (float*)hbh;                 // 4096 + 256 floats = 17.4 KB
    if (h2 == 1) {
        #pragma unroll
        for (int mf = 0; mf < 4; mf++)
            *(f32x4*)&cb[((rg * 4 + mf) * 64 + lane) * 4] = acc[mf];
        cb[4096 + rg * 64 + lane] = accl[0];
    }
    __syncthreads();
    if (h2 == 0) {
        #pragma unroll
        for (int mf = 0; mf < 4; mf++) {
            f32x4 o = *(const f32x4*)&cb[((rg * 4 + mf) * 64 + lane) * 4];
            acc[mf] += o;
        }
        float li = accl[0] + cb[4096 + rg * 64 + lane];
        const float invN = 1.0f / NN;
        float rl = 1.f / li;
        int row = i0 + rg * 16 + am;
        float* orow = outp + (size_t)row * (HH * FF) + h * FF;
        #pragma unroll
        for (int mf = 0; mf < 4; mf++) {
            float4 ov;
            #pragma unroll
            for (int r = 0; r < 4; r++) {
                int f = mf * 16 + aq * 4 + r;
                float v;
                if (li > 0.f) v = acc[mf][r] * rl;
                else          v = hpsum[h * FF + f] * invN;   // all-masked row fallback
                v = v > 0.f ? v : __expf(v) - 1.f;
                f4s(ov, r, v);
            }
            *(float4*)(orow + mf * 16 + aq * 4) = ov;
        }
    }
}

extern "C" void kernel_launch(void* const* d_in, const int* in_sizes, int n_in,
                              void* d_out, int out_size, void* d_ws, size_t ws_size,
                              hipStream_t stream) {
    const float* hmat = (const float*)d_in[0];
    const int*   adj  = (const int*)d_in[1];
    const float* W    = (const float*)d_in[2];
    const float* a    = (const float*)d_in[3];
    float* out = (float*)d_out;

    char* ws = (char*)d_ws;
    unsigned short* hpT_hi = (unsigned short*)(ws);                 // 4 MB
    unsigned long long* adjm = (unsigned long long*)(ws + (4u << 20)); // 2 MB
    unsigned short* wt_hi  = (unsigned short*)(ws + (6u << 20));    // 512 KB
    unsigned short* wt_lo  = (unsigned short*)(ws + (6u << 20) + (512u << 10));
    float* fs    = (float*)(ws + (7u << 20));                       // 128 KB
    float* fd    = (float*)(ws + (7u << 20) + (128u << 10));        // 128 KB
    unsigned* mxkey = (unsigned*)(ws + (7u << 20) + (256u << 10));  // 64 B
    float* hpsum = (float*)(mxkey + 16);                            // 2 KB
    unsigned short* h_hi = (unsigned short*)(ws + (8u << 20));      // 4 MB
    unsigned short* h_lo = (unsigned short*)(ws + (12u << 20));     // 4 MB

    k_prep   <<<dim3(2369),          256, 0, stream>>>(adj, W, hmat, adjm, wt_hi, wt_lo,
                                                       h_hi, h_lo, mxkey, hpsum);
    k_hp_mfma<<<dim3(64, 8),         256, 0, stream>>>(h_hi, h_lo, wt_hi, wt_lo, a,
                                                       hpT_hi, fs, fd, hpsum, mxkey);
    k_attn   <<<dim3(NN / 64, HH),   512, 0, stream>>>(fs, fd, mxkey, adjm,
                                                       hpT_hi, hpsum, out);
}